// Round 1
// baseline (259706.396 us; speedup 1.0000x reference)
//
#include <hip/hip_runtime.h>

typedef __attribute__((ext_vector_type(4))) float f32x4;
typedef __attribute__((ext_vector_type(8))) short short8;
typedef unsigned int u32;
typedef unsigned short u16;

#define T_SEQ 4096
#define HDIM  2048
#define GDIM  8192   // 4*H
#define INDIM 512
#define NBLK  256    // recurrence blocks
#define FLAG_STRIDE 32  // ints -> 128B per flag line

__device__ __forceinline__ u16 f2bf(float x) {
  u32 u = __float_as_uint(x);
  return (u16)((u + 0x7fffu + ((u >> 16) & 1u)) >> 16);  // RNE
}

// ---------------- prep kernels ----------------
__global__ void k_zero_f32(float* __restrict__ p, int n) {
  int i = blockIdx.x * blockDim.x + threadIdx.x;
  int st = gridDim.x * blockDim.x;
  for (; i < n; i += st) p[i] = 0.f;
}

__global__ void k_bias_sum(const float* __restrict__ a, const float* __restrict__ b,
                           float* __restrict__ o, int n) {
  int i = blockIdx.x * blockDim.x + threadIdx.x;
  if (i < n) o[i] = a[i] + b[i];
}

__global__ void k_cvt_bf16(const float* __restrict__ in, u16* __restrict__ out, int n) {
  int i = blockIdx.x * blockDim.x + threadIdx.x;
  int st = gridDim.x * blockDim.x;
  for (; i < n; i += st) out[i] = f2bf(in[i]);
}

// ---------------- bf16 MFMA GEMM:  C[M,N] = A[M,K] * B[N,K]^T + bias[N] ----------------
// 128x128 tile, BK=64, 4 waves (2x2 quadrants of 64x64), 16x16x32 MFMA,
// XOR-swizzled LDS (slot ^= row&7) to kill the stride-128B bank conflict (G4/T2).
__global__ __launch_bounds__(256) void gemm_bt_bias(
    const u16* __restrict__ A, const u16* __restrict__ B,
    const float* __restrict__ bias, float* __restrict__ C,
    int M, int N, int K)
{
  __shared__ u16 As[128 * 64];
  __shared__ u16 Bs[128 * 64];
  const int tid = threadIdx.x;
  const int m0 = blockIdx.y * 128;
  const int n0 = blockIdx.x * 128;
  const int w = tid >> 6;
  const int lane = tid & 63;
  const int wm = (w >> 1) * 64, wn = (w & 1) * 64;
  const int lr = lane & 15, lk = lane >> 4;

  f32x4 acc[4][4];
  f32x4 zero = {0.f, 0.f, 0.f, 0.f};
#pragma unroll
  for (int i = 0; i < 4; ++i) {
#pragma unroll
    for (int j = 0; j < 4; ++j) acc[i][j] = zero;
  }

  const int r = tid >> 1;           // 0..127 (tile row)
  const int sbase = (tid & 1) * 4;  // slot base (each slot = 8 bf16 = 16B)

  for (int kt = 0; kt < K; kt += 64) {
    const u16* ga = A + (size_t)(m0 + r) * K + kt + sbase * 8;
    const u16* gb = B + (size_t)(n0 + r) * K + kt + sbase * 8;
    uint4 va[4], vb[4];
#pragma unroll
    for (int s = 0; s < 4; ++s) {
      va[s] = *reinterpret_cast<const uint4*>(ga + s * 8);
      vb[s] = *reinterpret_cast<const uint4*>(gb + s * 8);
    }
    __syncthreads();  // previous iter's reads done before overwrite
#pragma unroll
    for (int s = 0; s < 4; ++s) {
      int ps = (sbase + s) ^ (r & 7);
      *reinterpret_cast<uint4*>(&As[r * 64 + ps * 8]) = va[s];
      *reinterpret_cast<uint4*>(&Bs[r * 64 + ps * 8]) = vb[s];
    }
    __syncthreads();
#pragma unroll
    for (int k32 = 0; k32 < 2; ++k32) {
      short8 af[4], bg[4];
#pragma unroll
      for (int i = 0; i < 4; ++i) {
        int arow = wm + i * 16 + lr;
        int aslot = (k32 * 4 + lk) ^ (arow & 7);
        af[i] = *reinterpret_cast<const short8*>(&As[arow * 64 + aslot * 8]);
        int brow = wn + i * 16 + lr;
        int bslot = (k32 * 4 + lk) ^ (brow & 7);
        bg[i] = *reinterpret_cast<const short8*>(&Bs[brow * 64 + bslot * 8]);
      }
#pragma unroll
      for (int i = 0; i < 4; ++i) {
#pragma unroll
        for (int j = 0; j < 4; ++j) {
          acc[i][j] = __builtin_amdgcn_mfma_f32_16x16x32_bf16(af[i], bg[j], acc[i][j], 0, 0, 0);
        }
      }
    }
  }

  // epilogue: C/D layout col = lane&15, row = (lane>>4)*4 + reg  [m89-verified]
#pragma unroll
  for (int j = 0; j < 4; ++j) {
    int gcol = n0 + wn + j * 16 + lr;
    float bv = bias[gcol];
#pragma unroll
    for (int i = 0; i < 4; ++i) {
      int grow = m0 + wm + i * 16 + lk * 4;
#pragma unroll
      for (int rr = 0; rr < 4; ++rr) {
        C[(size_t)(grow + rr) * N + gcol] = acc[i][j][rr] + bv;
      }
    }
  }
}

// ---------------- persistent LSTM recurrence ----------------
// 256 blocks x 512 threads. Block owns h[bid*8 .. bid*8+8) -> 32 gate rows.
// W_hh rows register-resident fp32 (128 VGPR/lane). Per step:
//   poll 256 producer flags (agent acquire) -> stage h[t] row into LDS ->
//   32 dots (16 lanes/row, k interleaved for 2-way-max LDS banking) ->
//   shfl reduce -> gates -> c,h update -> tid0 funnels h slice to global,
//   release-stores flag = t+1. Fresh h row per step => no stale-line hazard.
__global__ __launch_bounds__(512, 2) void lstm_rec(
    const float* __restrict__ gx,    // [T][8192] precomputed input contribution (+biases)
    const float* __restrict__ Whh,   // [8192][2048] fp32
    float* __restrict__ hhist,       // [T+1][2048], row 0 pre-zeroed
    u16* __restrict__ hbf,           // [T][2048] bf16 copy of outputs, or nullptr
    int* __restrict__ flags,         // [NBLK*FLAG_STRIDE], pre-zeroed
    int T)
{
  const int tid = threadIdx.x;
  const int bid = blockIdx.x;
  const int sub = tid & 15;        // k-splitter within a row (16 per row)
  const int row_local = tid >> 4;  // 0..31
  const int q = row_local >> 3, jj = row_local & 7;
  const int grow = q * HDIM + bid * 8 + jj;  // global gate row

  // register-resident weight slice: k = sub*4 + 64*i, i=0..31 (float4 chunks)
  float4 wreg[32];
  const float* wrow = Whh + (size_t)grow * HDIM + sub * 4;
#pragma unroll
  for (int i = 0; i < 32; ++i) wreg[i] = *reinterpret_cast<const float4*>(wrow + 64 * i);

  __shared__ float h_lds[HDIM];
  __shared__ float gg[32];
  __shared__ float c_s[8];
  __shared__ float h_s[8];
  if (tid < 8) c_s[tid] = 0.f;

  for (int t = 0; t < T; ++t) {
    // prefetch gx early (independent of h); stays in flight across the poll
    float gxv = 0.f;
    if (sub == 0) gxv = gx[(size_t)t * GDIM + grow];

    // wait for all producers of h[t]
    if (tid < NBLK) {
      while (__hip_atomic_load(&flags[tid * FLAG_STRIDE], __ATOMIC_ACQUIRE,
                               __HIP_MEMORY_SCOPE_AGENT) < t) { /* spin */ }
    }
    __syncthreads();

    // stage h[t] into LDS (8KB, coalesced float4)
    const float* hrow = hhist + (size_t)t * HDIM;
    *reinterpret_cast<float4*>(&h_lds[tid * 4]) =
        *reinterpret_cast<const float4*>(hrow + tid * 4);
    __syncthreads();

    // dot: 128 MACs/lane, 4 independent accumulators
    f32x4 a = {0.f, 0.f, 0.f, 0.f};
#pragma unroll
    for (int i = 0; i < 32; ++i) {
      float4 hv = *reinterpret_cast<const float4*>(&h_lds[sub * 4 + 64 * i]);
      a.x += wreg[i].x * hv.x;
      a.y += wreg[i].y * hv.y;
      a.z += wreg[i].z * hv.z;
      a.w += wreg[i].w * hv.w;
    }
    float acc = (a.x + a.y) + (a.z + a.w);
    acc += __shfl_xor(acc, 8, 16);
    acc += __shfl_xor(acc, 4, 16);
    acc += __shfl_xor(acc, 2, 16);
    acc += __shfl_xor(acc, 1, 16);
    if (sub == 0) gg[row_local] = acc + gxv;
    __syncthreads();

    // gates (PyTorch order i,f,g,o) for the block's 8 h elements
    if (tid < 8) {
      float gi = gg[tid], gf = gg[8 + tid], gc = gg[16 + tid], go = gg[24 + tid];
      float i_ = 1.f / (1.f + expf(-gi));
      float f_ = 1.f / (1.f + expf(-gf));
      float g_ = tanhf(gc);
      float o_ = 1.f / (1.f + expf(-go));
      float c = f_ * c_s[tid] + i_ * g_;
      c_s[tid] = c;
      h_s[tid] = o_ * tanhf(c);
    }
    __syncthreads();

    // single-thread funnel: stores + release are by one thread => fence is valid
    if (tid == 0) {
      float* dst = hhist + (size_t)(t + 1) * HDIM + bid * 8;
      float4 h0, h1;
      h0.x = h_s[0]; h0.y = h_s[1]; h0.z = h_s[2]; h0.w = h_s[3];
      h1.x = h_s[4]; h1.y = h_s[5]; h1.z = h_s[6]; h1.w = h_s[7];
      *reinterpret_cast<float4*>(dst) = h0;
      *reinterpret_cast<float4*>(dst + 4) = h1;
      if (hbf) {
        uint4 hb;
        hb.x = (u32)f2bf(h_s[0]) | ((u32)f2bf(h_s[1]) << 16);
        hb.y = (u32)f2bf(h_s[2]) | ((u32)f2bf(h_s[3]) << 16);
        hb.z = (u32)f2bf(h_s[4]) | ((u32)f2bf(h_s[5]) << 16);
        hb.w = (u32)f2bf(h_s[6]) | ((u32)f2bf(h_s[7]) << 16);
        *reinterpret_cast<uint4*>(hbf + (size_t)t * HDIM + bid * 8) = hb;
      }
      __threadfence();  // belt & suspenders; release below orders prior writes
      __hip_atomic_store(&flags[bid * FLAG_STRIDE], t + 1, __ATOMIC_RELEASE,
                         __HIP_MEMORY_SCOPE_AGENT);
    }
  }
}

// ---------------- heads: two 2048-dots ----------------
__global__ void k_heads(const float* __restrict__ h, const float* __restrict__ wt,
                        const float* __restrict__ bt, const float* __restrict__ wf,
                        const float* __restrict__ bfp, float* __restrict__ out) {
  int tid = threadIdx.x;  // 256
  float st = 0.f, sf = 0.f;
  for (int i = tid; i < HDIM; i += 256) {
    float hv = h[i];
    st += hv * wt[i];
    sf += hv * wf[i];
  }
#pragma unroll
  for (int m = 32; m >= 1; m >>= 1) {
    st += __shfl_xor(st, m, 64);
    sf += __shfl_xor(sf, m, 64);
  }
  __shared__ float ra[4], rb[4];
  if ((tid & 63) == 0) { ra[tid >> 6] = st; rb[tid >> 6] = sf; }
  __syncthreads();
  if (tid == 0) {
    out[0] = ra[0] + ra[1] + ra[2] + ra[3] + bt[0];
    out[1] = rb[0] + rb[1] + rb[2] + rb[3] + bfp[0];
  }
}

// ---------------- launch ----------------
extern "C" void kernel_launch(void* const* d_in, const int* in_sizes, int n_in,
                              void* d_out, int out_size, void* d_ws, size_t ws_size,
                              hipStream_t stream) {
  const float* x     = (const float*)d_in[0];
  const float* w_ih0 = (const float*)d_in[1];
  const float* w_hh0 = (const float*)d_in[2];
  const float* b_ih0 = (const float*)d_in[3];
  const float* b_hh0 = (const float*)d_in[4];
  const float* w_ih1 = (const float*)d_in[5];
  const float* w_hh1 = (const float*)d_in[6];
  const float* b_ih1 = (const float*)d_in[7];
  const float* b_hh1 = (const float*)d_in[8];
  const float* w_t   = (const float*)d_in[9];
  const float* b_t   = (const float*)d_in[10];
  const float* w_f   = (const float*)d_in[11];
  const float* b_f   = (const float*)d_in[12];

  // workspace layout (bytes). Total ~252.2 MiB.
  char* p = (char*)d_ws;
  float* gx    = (float*)(p);                 // 4096*8192*4  = 134217728 (reused by both layers)
  float* hs0f  = (float*)(p + 134217728);     // 4097*2048*4  = 33562624
  float* h1f   = (float*)(p + 167780352);     // 4097*2048*4  = 33562624
  u16*   xb    = (u16*)  (p + 201342976);     // 4096*512*2   = 4194304
  u16*   wb0   = (u16*)  (p + 205537280);     // 8192*512*2   = 8388608
  u16*   wb1   = (u16*)  (p + 213925888);     // 8192*2048*2  = 33554432
  u16*   hs0b  = (u16*)  (p + 247480320);     // 4096*2048*2  = 16777216
  float* bias0 = (float*)(p + 264257536);     // 8192*4
  float* bias1 = (float*)(p + 264290304);     // 8192*4
  int*   flags0= (int*)  (p + 264323072);     // 256*32*4
  int*   flags1= (int*)  (p + 264355840);     // 256*32*4

  // init (re-run every launch => deterministic replay)
  k_zero_f32<<<8, 256, 0, stream>>>(hs0f, HDIM);                 // h0(-1) = 0
  k_zero_f32<<<8, 256, 0, stream>>>(h1f, HDIM);                  // h1(-1) = 0
  k_zero_f32<<<64, 256, 0, stream>>>((float*)flags0, 2 * NBLK * FLAG_STRIDE);
  k_bias_sum<<<GDIM / 256, 256, 0, stream>>>(b_ih0, b_hh0, bias0, GDIM);
  k_bias_sum<<<GDIM / 256, 256, 0, stream>>>(b_ih1, b_hh1, bias1, GDIM);
  k_cvt_bf16<<<1024, 256, 0, stream>>>(x, xb, T_SEQ * INDIM);
  k_cvt_bf16<<<1024, 256, 0, stream>>>(w_ih0, wb0, GDIM * INDIM);
  k_cvt_bf16<<<2048, 256, 0, stream>>>(w_ih1, wb1, GDIM * HDIM);

  // layer 0: gx0 = x @ w_ih0^T + (b_ih0 + b_hh0); then recurrence
  gemm_bt_bias<<<dim3(GDIM / 128, T_SEQ / 128), 256, 0, stream>>>(
      xb, wb0, bias0, gx, T_SEQ, GDIM, INDIM);
  lstm_rec<<<NBLK, 512, 0, stream>>>(gx, w_hh0, hs0f, hs0b, flags0, T_SEQ);

  // layer 1: gx1 = hs0 @ w_ih1^T + (b_ih1 + b_hh1); then recurrence
  gemm_bt_bias<<<dim3(GDIM / 128, T_SEQ / 128), 256, 0, stream>>>(
      hs0b, wb1, bias1, gx, T_SEQ, GDIM, HDIM);
  lstm_rec<<<NBLK, 512, 0, stream>>>(gx, w_hh1, h1f, (u16*)nullptr, flags1, T_SEQ);

  // heads on h1[T]
  k_heads<<<1, 256, 0, stream>>>(h1f + (size_t)T_SEQ * HDIM, w_t, b_t, w_f, b_f,
                                 (float*)d_out);
}